// Round 15
// baseline (360.362 us; speedup 1.0000x reference)
//
#include <hip/hip_runtime.h>

#define NB 8
#define CH 8
#define N1S 255
#define CROP 257
#define NOUT 255
#define CC (CROP * CROP)   // 66049

static constexpr float PI2 = 6.28318530717958647692f;

__device__ inline unsigned short f2bf(float f) {
  unsigned int u = __float_as_uint(f);
  unsigned int lsb = (u >> 16) & 1u;
  u += 0x7fffu + lsb;
  return (unsigned short)(u >> 16);
}

__global__ void k_fill(unsigned short* __restrict__ out, int n, float v) {
  int i = blockIdx.x * 256 + threadIdx.x;
  if (i < n) out[i] = f2bf(v);
}

// ---------------- trig tables ----------------
__global__ void k_tables(float* __restrict__ T, float* __restrict__ Tt,
                         float2* __restrict__ D, float2* __restrict__ Dt) {
  int idx = blockIdx.x * blockDim.x + threadIdx.x;
  if (idx < CROP * N1S) {
    int a = idx / N1S, p = idx % N1S;
    int v = (p + 1) * (a - 128);
    int t = v % 512; if (t < 0) t += 512; if (t >= 256) t -= 512;
    float s = sinf((float)t * (PI2 / 512.0f));
    T[a * N1S + p] = s;
    Tt[p * CROP + a] = s;
  }
  if (idx < NOUT * CROP) {
    int k = idx / CROP, j = idx % CROP;
    int v = k * (j - 127);
    int t = v % 513; if (t < 0) t += 513; if (t > 256) t -= 513;
    float ang = (float)t * (PI2 / 513.0f);
    float2 d = make_float2(cosf(ang), -sinf(ang));
    D[k * CROP + j] = d;
    Dt[j * NOUT + k] = d;
  }
}

// ======== LDS-tiled GEMM kernels: 32x64 tile, 512 thr, 4 out/thr (validated r13) ========

__global__ __launch_bounds__(512) void k_dst1(const float* __restrict__ r,
                                              const float* __restrict__ T,
                                              float* __restrict__ tmp) {
  __shared__ float As[32][16];
  __shared__ float Bs[16][64];
  const int tx = threadIdx.x, ty = threadIdx.y;
  const int tid = ty * 64 + tx;
  const int b = blockIdx.z;
  const int n = blockIdx.x * 64 + tx;
  const int a_base = blockIdx.y * 32;
  const float* rb = r + (size_t)b * N1S * N1S;
  float acc[4] = {};
  for (int mc = 0; mc < N1S; mc += 16) {
    { int row = tid / 16, col = tid % 16;
      int a = a_base + row, m = mc + col;
      As[row][col] = (a < CROP && m < N1S) ? T[a * N1S + m] : 0.f; }
    { int row = tid / 64, col = tid % 64;
      #pragma unroll
      for (int rr = 0; rr < 2; ++rr) {
        int m = mc + row + rr * 8, nn = blockIdx.x * 64 + col;
        Bs[row + rr * 8][col] = (m < N1S && nn < N1S) ? rb[m * N1S + nn] : 0.f;
      } }
    __syncthreads();
    #pragma unroll
    for (int jj = 0; jj < 16; ++jj) {
      float x = Bs[jj][tx];
      #pragma unroll
      for (int q = 0; q < 4; ++q)
        acc[q] = fmaf(As[ty * 4 + q][jj], x, acc[q]);
    }
    __syncthreads();
  }
  if (n < N1S) {
    #pragma unroll
    for (int q = 0; q < 4; ++q) {
      int a = a_base + ty * 4 + q;
      if (a < CROP) tmp[((size_t)b * CROP + a) * N1S + n] = acc[q];
    }
  }
}

__global__ __launch_bounds__(512) void k_dst2(const float* __restrict__ tmp,
                                              const float* __restrict__ Tt,
                                              float2* __restrict__ z0) {
  __shared__ float As[32][16];
  __shared__ float Bs[16][64];
  const int tx = threadIdx.x, ty = threadIdx.y;
  const int tid = ty * 64 + tx;
  const int b = blockIdx.z;
  const int a2 = blockIdx.x * 64 + tx;
  const int a_base = blockIdx.y * 32;
  const float* tb = tmp + (size_t)b * CROP * N1S;
  float acc[4] = {};
  for (int nc = 0; nc < N1S; nc += 16) {
    { int row = tid / 16, col = tid % 16;
      int a1 = a_base + row, nn = nc + col;
      As[row][col] = (a1 < CROP && nn < N1S) ? tb[a1 * N1S + nn] : 0.f; }
    { int row = tid / 64, col = tid % 64;
      #pragma unroll
      for (int rr = 0; rr < 2; ++rr) {
        int nn = nc + row + rr * 8, aa2 = blockIdx.x * 64 + col;
        Bs[row + rr * 8][col] = (nn < N1S && aa2 < CROP) ? Tt[nn * CROP + aa2] : 0.f;
      } }
    __syncthreads();
    #pragma unroll
    for (int jj = 0; jj < 16; ++jj) {
      float x = Bs[jj][tx];
      #pragma unroll
      for (int q = 0; q < 4; ++q)
        acc[q] = fmaf(As[ty * 4 + q][jj], x, acc[q]);
    }
    __syncthreads();
  }
  if (a2 < CROP) {
    #pragma unroll
    for (int q = 0; q < 4; ++q) {
      int a1 = a_base + ty * 4 + q;
      if (a1 < CROP)
        z0[((size_t)b * CROP + a1) * CROP + a2] = make_float2(acc[q] * (-1.0f / 65536.0f), 0.f);
    }
  }
}

__global__ __launch_bounds__(512) void k_f1(const float2* __restrict__ z,
                                            const float2* __restrict__ D,
                                            float2* __restrict__ t) {
  __shared__ float2 As[32][16];
  __shared__ float2 Bs[16][64];
  const int tx = threadIdx.x, ty = threadIdx.y;
  const int tid = ty * 64 + tx;
  const int b = blockIdx.z;
  const int j2 = blockIdx.x * 64 + tx;
  const int k_base = blockIdx.y * 32;
  const float2* zb = z + (size_t)b * CC;
  float tr[4] = {}, ti[4] = {};
  for (int jc = 0; jc < CROP; jc += 16) {
    { int row = tid / 16, col = tid % 16;
      int k = k_base + row, j1 = jc + col;
      As[row][col] = (k < NOUT && j1 < CROP) ? D[k * CROP + j1] : make_float2(0.f, 0.f); }
    { int row = tid / 64, col = tid % 64;
      #pragma unroll
      for (int rr = 0; rr < 2; ++rr) {
        int j1 = jc + row + rr * 8, jj2 = blockIdx.x * 64 + col;
        Bs[row + rr * 8][col] = (j1 < CROP && jj2 < CROP) ? zb[j1 * CROP + jj2] : make_float2(0.f, 0.f);
      } }
    __syncthreads();
    #pragma unroll
    for (int jj = 0; jj < 16; ++jj) {
      float2 zv = Bs[jj][tx];
      #pragma unroll
      for (int q = 0; q < 4; ++q) {
        float2 d = As[ty * 4 + q][jj];
        tr[q] = fmaf(d.x, zv.x, tr[q]); tr[q] = fmaf(-d.y, zv.y, tr[q]);
        ti[q] = fmaf(d.x, zv.y, ti[q]); ti[q] = fmaf(d.y, zv.x, ti[q]);
      }
    }
    __syncthreads();
  }
  if (j2 < CROP) {
    #pragma unroll
    for (int q = 0; q < 4; ++q) {
      int k = k_base + ty * 4 + q;
      if (k < NOUT)
        t[((size_t)b * NOUT + k) * CROP + j2] = make_float2(tr[q], ti[q]);
    }
  }
}

__global__ __launch_bounds__(512) void k_f2(const float2* __restrict__ t,
                                            const float2* __restrict__ Dt,
                                            ushort2* __restrict__ out) {
  __shared__ float2 As[32][16];
  __shared__ float2 Bs[16][64];
  const int tx = threadIdx.x, ty = threadIdx.y;
  const int tid = ty * 64 + tx;
  const int b = blockIdx.z;
  const int k2 = blockIdx.x * 64 + tx;
  const int k_base = blockIdx.y * 32;
  const float2* tb = t + (size_t)b * NOUT * CROP;
  float er[4] = {}, ei[4] = {};
  for (int jc = 0; jc < CROP; jc += 16) {
    { int row = tid / 16, col = tid % 16;
      int k1 = k_base + row, j = jc + col;
      As[row][col] = (k1 < NOUT && j < CROP) ? tb[k1 * CROP + j] : make_float2(0.f, 0.f); }
    { int row = tid / 64, col = tid % 64;
      #pragma unroll
      for (int rr = 0; rr < 2; ++rr) {
        int j = jc + row + rr * 8, kk2 = blockIdx.x * 64 + col;
        Bs[row + rr * 8][col] = (j < CROP && kk2 < NOUT) ? Dt[j * NOUT + kk2] : make_float2(0.f, 0.f);
      } }
    __syncthreads();
    #pragma unroll
    for (int jj = 0; jj < 16; ++jj) {
      float2 dv = Bs[jj][tx];
      #pragma unroll
      for (int q = 0; q < 4; ++q) {
        float2 tv = As[ty * 4 + q][jj];
        er[q] = fmaf(tv.x, dv.x, er[q]); er[q] = fmaf(-tv.y, dv.y, er[q]);
        ei[q] = fmaf(tv.x, dv.y, ei[q]); ei[q] = fmaf(tv.y, dv.x, ei[q]);
      }
    }
    __syncthreads();
  }
  if (k2 < NOUT) {
    #pragma unroll
    for (int q = 0; q < 4; ++q) {
      int k1 = k_base + ty * 4 + q;
      if (k1 < NOUT)
        out[((size_t)b * NOUT + k1) * NOUT + k2] = make_ushort2(f2bf(ei[q]), f2bf(er[q]));
    }
  }
}

// ---------------- conv: 16x32 output tile, 2 pixels/thread, scalar weight path ----------------
template<int CIN, int COUT, bool TRANS, bool THETA, bool REALIN>
__global__ __launch_bounds__(256) void k_conv(const float2* __restrict__ in,
                                              const float* __restrict__ wre,
                                              const float* __restrict__ wim,
                                              const float* __restrict__ tre,
                                              const float* __restrict__ tim,
                                              float2* __restrict__ out) {
  __shared__ float2 tile[CIN][34][18];
  const int b = blockIdx.z;
  const int tx = threadIdx.x, ty = threadIdx.y;
  const int tid = ty * 16 + tx;
  const int ox0 = blockIdx.x * 16, oy0 = blockIdx.y * 32;

  const float2* inb = in + (size_t)b * CIN * CC;
  for (int idx = tid; idx < CIN * 34 * 18; idx += 256) {
    int c = idx / (34 * 18), rem = idx % (34 * 18);
    int iy = rem / 18, ix = rem % 18;
    int gy = oy0 + iy - 1, gx = ox0 + ix - 1;
    float2 v = make_float2(0.f, 0.f);
    if (gy >= 0 && gy < CROP && gx >= 0 && gx < CROP)
      v = inb[(c * CROP + gy) * CROP + gx];
    tile[c][iy][ix] = v;
  }
  __syncthreads();
  const int ox = ox0 + tx;
  const int oy1 = oy0 + ty, oy2 = oy0 + ty + 16;
  if (ox >= CROP) return;
  const bool v1 = oy1 < CROP, v2 = oy2 < CROP;
  float ar1[COUT], ai1[COUT], ar2[COUT], ai2[COUT];
  #pragma unroll
  for (int o = 0; o < COUT; ++o) { ar1[o] = ai1[o] = ar2[o] = ai2[o] = 0.f; }
  #pragma unroll 1
  for (int c = 0; c < CIN; ++c) {
    float xr1[9], xi1[9], xr2[9], xi2[9];
    #pragma unroll
    for (int t9 = 0; t9 < 9; ++t9) {
      float2 a = tile[c][ty + t9 / 3][tx + t9 % 3];
      float2 d = tile[c][ty + 16 + t9 / 3][tx + t9 % 3];
      xr1[t9] = a.x; xr2[t9] = d.x;
      if (!REALIN) { xi1[t9] = a.y; xi2[t9] = d.y; }
    }
    #pragma unroll
    for (int o = 0; o < COUT; ++o) {
      #pragma unroll
      for (int t9 = 0; t9 < 9; ++t9) {
        int di = t9 / 3, dj = t9 % 3;
        float wr, wi;
        if (TRANS) {
          int widx = (((b * CIN + c) * COUT + o) * 3 + dj) * 3 + di;
          wr = wre[widx]; wi = -wim[widx];
        } else {
          int widx = (((b * COUT + o) * CIN + c) * 3 + di) * 3 + dj;
          wr = wre[widx]; wi = wim[widx];
        }
        if (REALIN) {
          ar1[o] = fmaf(wr, xr1[t9], ar1[o]); ai1[o] = fmaf(wi, xr1[t9], ai1[o]);
          ar2[o] = fmaf(wr, xr2[t9], ar2[o]); ai2[o] = fmaf(wi, xr2[t9], ai2[o]);
        } else {
          ar1[o] = fmaf(wr, xr1[t9], ar1[o]); ar1[o] = fmaf(-wi, xi1[t9], ar1[o]);
          ai1[o] = fmaf(wr, xi1[t9], ai1[o]); ai1[o] = fmaf(wi, xr1[t9], ai1[o]);
          ar2[o] = fmaf(wr, xr2[t9], ar2[o]); ar2[o] = fmaf(-wi, xi2[t9], ar2[o]);
          ai2[o] = fmaf(wr, xi2[t9], ai2[o]); ai2[o] = fmaf(wi, xr2[t9], ai2[o]);
        }
      }
    }
  }
  float2* outb = out + (size_t)b * COUT * CC;
  #pragma unroll
  for (int o = 0; o < COUT; ++o) {
    float r1 = ar1[o], i1 = ai1[o], r2 = ar2[o], i2 = ai2[o];
    if (THETA) {
      if (v1) {
        size_t tix = ((size_t)(b * COUT + o) * CROP + oy1) * CROP + ox;
        float trv = tre[tix], tiv = tim[tix];
        float nr = r1 * trv - i1 * tiv, ni = r1 * tiv + i1 * trv;
        r1 = nr; i1 = ni;
      }
      if (v2) {
        size_t tix = ((size_t)(b * COUT + o) * CROP + oy2) * CROP + ox;
        float trv = tre[tix], tiv = tim[tix];
        float nr = r2 * trv - i2 * tiv, ni = r2 * tiv + i2 * trv;
        r2 = nr; i2 = ni;
      }
    }
    if (v1) outb[(o * CROP + oy1) * CROP + ox] = make_float2(r1, i1);
    if (v2) outb[(o * CROP + oy2) * CROP + ox] = make_float2(r2, i2);
  }
}

extern "C" void kernel_launch(void* const* d_in, const int* in_sizes, int n_in,
                              void* d_out, int out_size, void* d_ws, size_t ws_size,
                              hipStream_t stream) {
  (void)ws_size;
  static const int EXP[9] = {520200, 576, 576, 4608, 4608, 4608, 4608, 4227136, 4227136};
  int bad = -1;
  if (n_in != 9) bad = 90;
  else for (int i = 0; i < 9; ++i) if (in_sizes[i] != EXP[i]) { bad = i; break; }
  if (bad >= 0) {
    float v = (bad == 90) ? 99.0f : (100.0f + (float)bad);
    k_fill<<<(out_size + 255) / 256, 256, 0, stream>>>((unsigned short*)d_out, out_size, v);
    return;
  }

  const float* r    = (const float*)d_in[0];
  const float* w1re = (const float*)d_in[1];
  const float* w1im = (const float*)d_in[2];
  const float* w2re = (const float*)d_in[3];
  const float* w2im = (const float*)d_in[4];
  const float* w3re = (const float*)d_in[5];
  const float* w3im = (const float*)d_in[6];
  const float* thre = (const float*)d_in[7];
  const float* thim = (const float*)d_in[8];

  float* ws = (float*)d_ws;
  size_t off = 0;
  auto alloc = [&](size_t n) { float* p = ws + off; off += (n + 63) & ~(size_t)63; return p; };
  float*  T    = alloc((size_t)CROP * N1S);
  float*  Tt   = alloc((size_t)N1S * CROP);
  float2* D    = (float2*)alloc((size_t)NOUT * CROP * 2);
  float2* Dt   = (float2*)alloc((size_t)CROP * NOUT * 2);
  float*  tmpA = alloc((size_t)NB * CROP * N1S);
  float2* z0   = (float2*)alloc((size_t)NB * CC * 2);
  float2* tmpF = (float2*)alloc((size_t)NB * NOUT * CROP * 2);
  float2* A    = (float2*)alloc((size_t)NB * CH * CC * 2);
  float2* Bb   = (float2*)alloc((size_t)NB * CH * CC * 2);

  k_tables<<<dim3((CROP * N1S + 255) / 256), dim3(256), 0, stream>>>(T, Tt, D, Dt);
  k_dst1<<<dim3(4, 9, NB), dim3(64, 8), 0, stream>>>(r, T, tmpA);
  k_dst2<<<dim3(5, 9, NB), dim3(64, 8), 0, stream>>>(tmpA, Tt, z0);

  dim3 cgrid(17, 9, NB), cblk(16, 16);
  k_conv<1, 8, false, false, true ><<<cgrid, cblk, 0, stream>>>(z0, w1re, w1im, nullptr, nullptr, A);
  k_conv<8, 8, false, false, false><<<cgrid, cblk, 0, stream>>>(A, w2re, w2im, nullptr, nullptr, Bb);
  k_conv<8, 8, false, true , false><<<cgrid, cblk, 0, stream>>>(Bb, w3re, w3im, thre, thim, A);
  k_conv<8, 8, true,  false, false><<<cgrid, cblk, 0, stream>>>(A, w3re, w3im, nullptr, nullptr, Bb);
  k_conv<8, 8, true,  false, false><<<cgrid, cblk, 0, stream>>>(Bb, w2re, w2im, nullptr, nullptr, A);
  k_conv<8, 1, true,  false, false><<<cgrid, cblk, 0, stream>>>(A, w1re, w1im, nullptr, nullptr, z0);

  k_f1<<<dim3(5, 8, NB), dim3(64, 8), 0, stream>>>(z0, D, tmpF);
  k_f2<<<dim3(4, 8, NB), dim3(64, 8), 0, stream>>>(tmpF, Dt, (ushort2*)d_out);
}

// Round 16
// 335.321 us; speedup vs baseline: 1.0747x; 1.0747x over previous
//
#include <hip/hip_runtime.h>

#define NB 8
#define CH 8
#define N1S 255
#define CROP 257
#define NOUT 255
#define CC (CROP * CROP)   // 66049

static constexpr float PI2 = 6.28318530717958647692f;

__device__ inline unsigned short f2bf(float f) {
  unsigned int u = __float_as_uint(f);
  unsigned int lsb = (u >> 16) & 1u;
  u += 0x7fffu + lsb;
  return (unsigned short)(u >> 16);
}

__global__ void k_fill(unsigned short* __restrict__ out, int n, float v) {
  int i = blockIdx.x * 256 + threadIdx.x;
  if (i < n) out[i] = f2bf(v);
}

// ---------------- trig tables ----------------
__global__ void k_tables(float* __restrict__ T, float* __restrict__ Tt,
                         float2* __restrict__ D, float2* __restrict__ Dt) {
  int idx = blockIdx.x * blockDim.x + threadIdx.x;
  if (idx < CROP * N1S) {
    int a = idx / N1S, p = idx % N1S;
    int v = (p + 1) * (a - 128);
    int t = v % 512; if (t < 0) t += 512; if (t >= 256) t -= 512;
    float s = sinf((float)t * (PI2 / 512.0f));
    T[a * N1S + p] = s;
    Tt[p * CROP + a] = s;
  }
  if (idx < NOUT * CROP) {
    int k = idx / CROP, j = idx % CROP;
    int v = k * (j - 127);
    int t = v % 513; if (t < 0) t += 513; if (t > 256) t -= 513;
    float ang = (float)t * (PI2 / 513.0f);
    float2 d = make_float2(cosf(ang), -sinf(ang));
    D[k * CROP + j] = d;
    Dt[j * NOUT + k] = d;
  }
}

// ---------------- weight prep: pack per-layer weights in consumption order ----------------
// Layers (pair counts): L0 conv1(1->8,nonT)=576  L1 conv2(8->8,nonT)=4608  L2 conv3(8->8,nonT)=4608
//                       L3 convT3(8->8,T)=4608   L4 convT2(8->8,T)=4608    L5 convT1(8->1,T)=576
// wp pair layout per layer: [b][c][o][t9] -> (wr, wi_eff)
__global__ void k_wprep(const float* __restrict__ w1re, const float* __restrict__ w1im,
                        const float* __restrict__ w2re, const float* __restrict__ w2im,
                        const float* __restrict__ w3re, const float* __restrict__ w3im,
                        float* __restrict__ wp) {
  int p = blockIdx.x * 256 + threadIdx.x;
  if (p >= 19584) return;
  int l, off;
  if      (p < 576)   { l = 0; off = 0; }
  else if (p < 5184)  { l = 1; off = 576; }
  else if (p < 9792)  { l = 2; off = 5184; }
  else if (p < 14400) { l = 3; off = 9792; }
  else if (p < 19008) { l = 4; off = 14400; }
  else                { l = 5; off = 19008; }
  int q = p - off;
  int cin  = (l == 0) ? 1 : 8;
  int cout = (l == 5) ? 1 : 8;
  int per_b = cin * cout * 9;
  int b = q / per_b, rem = q % per_b;
  int c = rem / (cout * 9), rem2 = rem % (cout * 9);
  int o = rem2 / 9, t9 = rem2 % 9;
  int di = t9 / 3, dj = t9 % 3;
  const float *wre, *wim;
  if (l == 0 || l == 5) { wre = w1re; wim = w1im; }
  else if (l == 1 || l == 4) { wre = w2re; wim = w2im; }
  else { wre = w3re; wim = w3im; }
  bool trans = (l >= 3);
  float wr, wi;
  if (trans) {
    int widx = (((b * cin + c) * cout + o) * 3 + dj) * 3 + di;
    wr = wre[widx]; wi = -wim[widx];
  } else {
    int widx = (((b * cout + o) * cin + c) * 3 + di) * 3 + dj;
    wr = wre[widx]; wi = wim[widx];
  }
  wp[2 * p] = wr;
  wp[2 * p + 1] = wi;
}

// ======== LDS-tiled GEMM kernels: 32x64 tile, 512 thr, 4 out/thr (validated r13) ========

__global__ __launch_bounds__(512) void k_dst1(const float* __restrict__ r,
                                              const float* __restrict__ T,
                                              float* __restrict__ tmp) {
  __shared__ float As[32][16];
  __shared__ float Bs[16][64];
  const int tx = threadIdx.x, ty = threadIdx.y;
  const int tid = ty * 64 + tx;
  const int b = blockIdx.z;
  const int n = blockIdx.x * 64 + tx;
  const int a_base = blockIdx.y * 32;
  const float* rb = r + (size_t)b * N1S * N1S;
  float acc[4] = {};
  for (int mc = 0; mc < N1S; mc += 16) {
    { int row = tid / 16, col = tid % 16;
      int a = a_base + row, m = mc + col;
      As[row][col] = (a < CROP && m < N1S) ? T[a * N1S + m] : 0.f; }
    { int row = tid / 64, col = tid % 64;
      #pragma unroll
      for (int rr = 0; rr < 2; ++rr) {
        int m = mc + row + rr * 8, nn = blockIdx.x * 64 + col;
        Bs[row + rr * 8][col] = (m < N1S && nn < N1S) ? rb[m * N1S + nn] : 0.f;
      } }
    __syncthreads();
    #pragma unroll
    for (int jj = 0; jj < 16; ++jj) {
      float x = Bs[jj][tx];
      #pragma unroll
      for (int q = 0; q < 4; ++q)
        acc[q] = fmaf(As[ty * 4 + q][jj], x, acc[q]);
    }
    __syncthreads();
  }
  if (n < N1S) {
    #pragma unroll
    for (int q = 0; q < 4; ++q) {
      int a = a_base + ty * 4 + q;
      if (a < CROP) tmp[((size_t)b * CROP + a) * N1S + n] = acc[q];
    }
  }
}

__global__ __launch_bounds__(512) void k_dst2(const float* __restrict__ tmp,
                                              const float* __restrict__ Tt,
                                              float2* __restrict__ z0) {
  __shared__ float As[32][16];
  __shared__ float Bs[16][64];
  const int tx = threadIdx.x, ty = threadIdx.y;
  const int tid = ty * 64 + tx;
  const int b = blockIdx.z;
  const int a2 = blockIdx.x * 64 + tx;
  const int a_base = blockIdx.y * 32;
  const float* tb = tmp + (size_t)b * CROP * N1S;
  float acc[4] = {};
  for (int nc = 0; nc < N1S; nc += 16) {
    { int row = tid / 16, col = tid % 16;
      int a1 = a_base + row, nn = nc + col;
      As[row][col] = (a1 < CROP && nn < N1S) ? tb[a1 * N1S + nn] : 0.f; }
    { int row = tid / 64, col = tid % 64;
      #pragma unroll
      for (int rr = 0; rr < 2; ++rr) {
        int nn = nc + row + rr * 8, aa2 = blockIdx.x * 64 + col;
        Bs[row + rr * 8][col] = (nn < N1S && aa2 < CROP) ? Tt[nn * CROP + aa2] : 0.f;
      } }
    __syncthreads();
    #pragma unroll
    for (int jj = 0; jj < 16; ++jj) {
      float x = Bs[jj][tx];
      #pragma unroll
      for (int q = 0; q < 4; ++q)
        acc[q] = fmaf(As[ty * 4 + q][jj], x, acc[q]);
    }
    __syncthreads();
  }
  if (a2 < CROP) {
    #pragma unroll
    for (int q = 0; q < 4; ++q) {
      int a1 = a_base + ty * 4 + q;
      if (a1 < CROP)
        z0[((size_t)b * CROP + a1) * CROP + a2] = make_float2(acc[q] * (-1.0f / 65536.0f), 0.f);
    }
  }
}

__global__ __launch_bounds__(512) void k_f1(const float2* __restrict__ z,
                                            const float2* __restrict__ D,
                                            float2* __restrict__ t) {
  __shared__ float2 As[32][16];
  __shared__ float2 Bs[16][64];
  const int tx = threadIdx.x, ty = threadIdx.y;
  const int tid = ty * 64 + tx;
  const int b = blockIdx.z;
  const int j2 = blockIdx.x * 64 + tx;
  const int k_base = blockIdx.y * 32;
  const float2* zb = z + (size_t)b * CC;
  float tr[4] = {}, ti[4] = {};
  for (int jc = 0; jc < CROP; jc += 16) {
    { int row = tid / 16, col = tid % 16;
      int k = k_base + row, j1 = jc + col;
      As[row][col] = (k < NOUT && j1 < CROP) ? D[k * CROP + j1] : make_float2(0.f, 0.f); }
    { int row = tid / 64, col = tid % 64;
      #pragma unroll
      for (int rr = 0; rr < 2; ++rr) {
        int j1 = jc + row + rr * 8, jj2 = blockIdx.x * 64 + col;
        Bs[row + rr * 8][col] = (j1 < CROP && jj2 < CROP) ? zb[j1 * CROP + jj2] : make_float2(0.f, 0.f);
      } }
    __syncthreads();
    #pragma unroll
    for (int jj = 0; jj < 16; ++jj) {
      float2 zv = Bs[jj][tx];
      #pragma unroll
      for (int q = 0; q < 4; ++q) {
        float2 d = As[ty * 4 + q][jj];
        tr[q] = fmaf(d.x, zv.x, tr[q]); tr[q] = fmaf(-d.y, zv.y, tr[q]);
        ti[q] = fmaf(d.x, zv.y, ti[q]); ti[q] = fmaf(d.y, zv.x, ti[q]);
      }
    }
    __syncthreads();
  }
  if (j2 < CROP) {
    #pragma unroll
    for (int q = 0; q < 4; ++q) {
      int k = k_base + ty * 4 + q;
      if (k < NOUT)
        t[((size_t)b * NOUT + k) * CROP + j2] = make_float2(tr[q], ti[q]);
    }
  }
}

__global__ __launch_bounds__(512) void k_f2(const float2* __restrict__ t,
                                            const float2* __restrict__ Dt,
                                            ushort2* __restrict__ out) {
  __shared__ float2 As[32][16];
  __shared__ float2 Bs[16][64];
  const int tx = threadIdx.x, ty = threadIdx.y;
  const int tid = ty * 64 + tx;
  const int b = blockIdx.z;
  const int k2 = blockIdx.x * 64 + tx;
  const int k_base = blockIdx.y * 32;
  const float2* tb = t + (size_t)b * NOUT * CROP;
  float er[4] = {}, ei[4] = {};
  for (int jc = 0; jc < CROP; jc += 16) {
    { int row = tid / 16, col = tid % 16;
      int k1 = k_base + row, j = jc + col;
      As[row][col] = (k1 < NOUT && j < CROP) ? tb[k1 * CROP + j] : make_float2(0.f, 0.f); }
    { int row = tid / 64, col = tid % 64;
      #pragma unroll
      for (int rr = 0; rr < 2; ++rr) {
        int j = jc + row + rr * 8, kk2 = blockIdx.x * 64 + col;
        Bs[row + rr * 8][col] = (j < CROP && kk2 < NOUT) ? Dt[j * NOUT + kk2] : make_float2(0.f, 0.f);
      } }
    __syncthreads();
    #pragma unroll
    for (int jj = 0; jj < 16; ++jj) {
      float2 dv = Bs[jj][tx];
      #pragma unroll
      for (int q = 0; q < 4; ++q) {
        float2 tv = As[ty * 4 + q][jj];
        er[q] = fmaf(tv.x, dv.x, er[q]); er[q] = fmaf(-tv.y, dv.y, er[q]);
        ei[q] = fmaf(tv.x, dv.y, ei[q]); ei[q] = fmaf(tv.y, dv.x, ei[q]);
      }
    }
    __syncthreads();
  }
  if (k2 < NOUT) {
    #pragma unroll
    for (int q = 0; q < 4; ++q) {
      int k1 = k_base + ty * 4 + q;
      if (k1 < NOUT)
        out[((size_t)b * NOUT + k1) * NOUT + k2] = make_ushort2(f2bf(ei[q]), f2bf(er[q]));
    }
  }
}

// ---------------- conv: r14 geometry (16x16 tile, 1px/thread) + prepacked weights ----------------
// wl points at this layer's pack: pairs laid out [b][c][o][t9]; per c-iter 144 contiguous floats.
template<int CIN, int COUT, bool THETA, bool REALIN>
__global__ __launch_bounds__(256) void k_conv(const float2* __restrict__ in,
                                              const float* __restrict__ wl,
                                              const float* __restrict__ tre,
                                              const float* __restrict__ tim,
                                              float2* __restrict__ out) {
  __shared__ float2 tile[CIN][18][18];
  const int b = blockIdx.z;
  const int tx = threadIdx.x, ty = threadIdx.y;
  const int tid = ty * 16 + tx;
  const int ox0 = blockIdx.x * 16, oy0 = blockIdx.y * 16;

  const float2* inb = in + (size_t)b * CIN * CC;
  for (int c = 0; c < CIN; ++c) {
    for (int idx = tid; idx < 18 * 18; idx += 256) {
      int iy = idx / 18, ix = idx % 18;
      int gy = oy0 + iy - 1, gx = ox0 + ix - 1;
      float2 v = make_float2(0.f, 0.f);
      if (gy >= 0 && gy < CROP && gx >= 0 && gx < CROP)
        v = inb[(c * CROP + gy) * CROP + gx];
      tile[c][iy][ix] = v;
    }
  }
  __syncthreads();
  const int ox = ox0 + tx, oy = oy0 + ty;
  if (ox >= CROP || oy >= CROP) return;
  float accr[COUT], acci[COUT];
  #pragma unroll
  for (int o = 0; o < COUT; ++o) { accr[o] = 0.f; acci[o] = 0.f; }
  #pragma unroll 1
  for (int c = 0; c < CIN; ++c) {
    const float* wsc = wl + (size_t)2 * ((b * CIN + c) * COUT * 9);
    float xr[9], xi[9];
    #pragma unroll
    for (int t9 = 0; t9 < 9; ++t9) {
      float2 v = tile[c][ty + t9 / 3][tx + t9 % 3];
      xr[t9] = v.x; if (!REALIN) xi[t9] = v.y;
    }
    #pragma unroll
    for (int o = 0; o < COUT; ++o) {
      #pragma unroll
      for (int t9 = 0; t9 < 9; ++t9) {
        float wr = wsc[(o * 9 + t9) * 2];
        float wi = wsc[(o * 9 + t9) * 2 + 1];
        if (REALIN) {
          accr[o] = fmaf(wr, xr[t9], accr[o]);
          acci[o] = fmaf(wi, xr[t9], acci[o]);
        } else {
          accr[o] = fmaf(wr, xr[t9], accr[o]);
          accr[o] = fmaf(-wi, xi[t9], accr[o]);
          acci[o] = fmaf(wr, xi[t9], acci[o]);
          acci[o] = fmaf(wi, xr[t9], acci[o]);
        }
      }
    }
  }
  float2* outb = out + (size_t)b * COUT * CC;
  #pragma unroll
  for (int o = 0; o < COUT; ++o) {
    float orv = accr[o], oiv = acci[o];
    if (THETA) {
      size_t tix = ((size_t)(b * COUT + o) * CROP + oy) * CROP + ox;
      float trv = tre[tix], tiv = tim[tix];
      float nr = orv * trv - oiv * tiv;
      float ni = orv * tiv + oiv * trv;
      orv = nr; oiv = ni;
    }
    outb[(o * CROP + oy) * CROP + ox] = make_float2(orv, oiv);
  }
}

extern "C" void kernel_launch(void* const* d_in, const int* in_sizes, int n_in,
                              void* d_out, int out_size, void* d_ws, size_t ws_size,
                              hipStream_t stream) {
  (void)ws_size;
  static const int EXP[9] = {520200, 576, 576, 4608, 4608, 4608, 4608, 4227136, 4227136};
  int bad = -1;
  if (n_in != 9) bad = 90;
  else for (int i = 0; i < 9; ++i) if (in_sizes[i] != EXP[i]) { bad = i; break; }
  if (bad >= 0) {
    float v = (bad == 90) ? 99.0f : (100.0f + (float)bad);
    k_fill<<<(out_size + 255) / 256, 256, 0, stream>>>((unsigned short*)d_out, out_size, v);
    return;
  }

  const float* r    = (const float*)d_in[0];
  const float* w1re = (const float*)d_in[1];
  const float* w1im = (const float*)d_in[2];
  const float* w2re = (const float*)d_in[3];
  const float* w2im = (const float*)d_in[4];
  const float* w3re = (const float*)d_in[5];
  const float* w3im = (const float*)d_in[6];
  const float* thre = (const float*)d_in[7];
  const float* thim = (const float*)d_in[8];

  float* ws = (float*)d_ws;
  size_t off = 0;
  auto alloc = [&](size_t n) { float* p = ws + off; off += (n + 63) & ~(size_t)63; return p; };
  float*  T    = alloc((size_t)CROP * N1S);
  float*  Tt   = alloc((size_t)N1S * CROP);
  float2* D    = (float2*)alloc((size_t)NOUT * CROP * 2);
  float2* Dt   = (float2*)alloc((size_t)CROP * NOUT * 2);
  float*  wp   = alloc((size_t)2 * 19584);
  float*  tmpA = alloc((size_t)NB * CROP * N1S);
  float2* z0   = (float2*)alloc((size_t)NB * CC * 2);
  float2* tmpF = (float2*)alloc((size_t)NB * NOUT * CROP * 2);
  float2* A    = (float2*)alloc((size_t)NB * CH * CC * 2);
  float2* Bb   = (float2*)alloc((size_t)NB * CH * CC * 2);

  k_tables<<<dim3((CROP * N1S + 255) / 256), dim3(256), 0, stream>>>(T, Tt, D, Dt);
  k_wprep<<<dim3(77), dim3(256), 0, stream>>>(w1re, w1im, w2re, w2im, w3re, w3im, wp);
  k_dst1<<<dim3(4, 9, NB), dim3(64, 8), 0, stream>>>(r, T, tmpA);
  k_dst2<<<dim3(5, 9, NB), dim3(64, 8), 0, stream>>>(tmpA, Tt, z0);

  dim3 cgrid(17, 17, NB), cblk(16, 16);
  k_conv<1, 8, false, true ><<<cgrid, cblk, 0, stream>>>(z0, wp + 2 * 0,     nullptr, nullptr, A);
  k_conv<8, 8, false, false><<<cgrid, cblk, 0, stream>>>(A,  wp + 2 * 576,   nullptr, nullptr, Bb);
  k_conv<8, 8, true , false><<<cgrid, cblk, 0, stream>>>(Bb, wp + 2 * 5184,  thre, thim, A);
  k_conv<8, 8, false, false><<<cgrid, cblk, 0, stream>>>(A,  wp + 2 * 9792,  nullptr, nullptr, Bb);
  k_conv<8, 8, false, false><<<cgrid, cblk, 0, stream>>>(Bb, wp + 2 * 14400, nullptr, nullptr, A);
  k_conv<8, 1, false, false><<<cgrid, cblk, 0, stream>>>(A,  wp + 2 * 19008, nullptr, nullptr, z0);

  k_f1<<<dim3(5, 8, NB), dim3(64, 8), 0, stream>>>(z0, D, tmpF);
  k_f2<<<dim3(4, 8, NB), dim3(64, 8), 0, stream>>>(tmpF, Dt, (ushort2*)d_out);
}